// Round 2
// baseline (7597.775 us; speedup 1.0000x reference)
//
#include <hip/hip_runtime.h>
#include <math.h>

// Problem constants: B=64, S=128, E=512, H=512, A=256, V=8192, T=32
#define BB 64
#define SS 128
#define EE 512
#define HH 512
#define AA 256
#define VV 8192
#define TT 32

// ---------------------------------------------------------------------------
// fp32 GEMM (NT):  C[M,N] = A[M,K] * B[N,K]^T (+ bias[N]) (+ C if accum)
// Tiles: 64x64, BK=16, 256 threads, 4x4 microtile per thread.
// Requires M%64==0, N%64==0, K%16==0, lda/ldb mult of 4, 16B-aligned ptrs.
// ---------------------------------------------------------------------------
__global__ __launch_bounds__(256) void gemm_nt(
    const float* __restrict__ A, int lda,
    const float* __restrict__ B, int ldb,
    float* __restrict__ C, int ldc, int coff,
    const float* __restrict__ bias,
    int K, int accum)
{
    __shared__ float As[16][68];
    __shared__ float Bs[16][68];

    const int tid = threadIdx.x;
    const int m0 = blockIdx.x * 64;
    const int n0 = blockIdx.y * 64;
    const int row = tid >> 2;
    const int kq  = (tid & 3) * 4;
    const int tm  = tid >> 4;
    const int tn  = tid & 15;

    float acc[4][4] = {};

    for (int k0 = 0; k0 < K; k0 += 16) {
        float4 av = *(const float4*)(A + (size_t)(m0 + row) * lda + k0 + kq);
        float4 bv = *(const float4*)(B + (size_t)(n0 + row) * ldb + k0 + kq);
        As[kq + 0][row] = av.x; As[kq + 1][row] = av.y;
        As[kq + 2][row] = av.z; As[kq + 3][row] = av.w;
        Bs[kq + 0][row] = bv.x; Bs[kq + 1][row] = bv.y;
        Bs[kq + 2][row] = bv.z; Bs[kq + 3][row] = bv.w;
        __syncthreads();
#pragma unroll
        for (int k = 0; k < 16; ++k) {
            float4 a = *(const float4*)&As[k][tm * 4];
            float4 b = *(const float4*)&Bs[k][tn * 4];
            acc[0][0] += a.x * b.x; acc[0][1] += a.x * b.y; acc[0][2] += a.x * b.z; acc[0][3] += a.x * b.w;
            acc[1][0] += a.y * b.x; acc[1][1] += a.y * b.y; acc[1][2] += a.y * b.z; acc[1][3] += a.y * b.w;
            acc[2][0] += a.z * b.x; acc[2][1] += a.z * b.y; acc[2][2] += a.z * b.z; acc[2][3] += a.z * b.w;
            acc[3][0] += a.w * b.x; acc[3][1] += a.w * b.y; acc[3][2] += a.w * b.z; acc[3][3] += a.w * b.w;
        }
        __syncthreads();
    }

    float4 bi = make_float4(0.f, 0.f, 0.f, 0.f);
    if (bias) bi = *(const float4*)(bias + n0 + tn * 4);
#pragma unroll
    for (int i = 0; i < 4; ++i) {
        float* cp = C + (size_t)coff + (size_t)(m0 + tm * 4 + i) * ldc + n0 + tn * 4;
        float4 r;
        r.x = acc[i][0] + bi.x; r.y = acc[i][1] + bi.y;
        r.z = acc[i][2] + bi.z; r.w = acc[i][3] + bi.w;
        if (accum) {
            float4 old = *(const float4*)cp;
            r.x += old.x; r.y += old.y; r.z += old.z; r.w += old.w;
        }
        *(float4*)cp = r;
    }
}

// ---------------------------------------------------------------------------
// fp32 GEMM (NN):  C[M,N] = A[M,K] * B[K,N]  (B row-major [K,N])
// Same tiling. Used for enc_proj.
// ---------------------------------------------------------------------------
__global__ __launch_bounds__(256) void gemm_nn(
    const float* __restrict__ A, int lda,
    const float* __restrict__ B, int ldb,
    float* __restrict__ C, int ldc,
    int K)
{
    __shared__ float As[16][68];
    __shared__ float Bs[16][68];

    const int tid = threadIdx.x;
    const int m0 = blockIdx.x * 64;
    const int n0 = blockIdx.y * 64;
    const int row = tid >> 2;          // 0..63  (A stage)
    const int kq  = (tid & 3) * 4;
    const int kk  = tid >> 4;          // 0..15  (B stage)
    const int nq  = (tid & 15) * 4;
    const int tm  = tid >> 4;
    const int tn  = tid & 15;

    float acc[4][4] = {};

    for (int k0 = 0; k0 < K; k0 += 16) {
        float4 av = *(const float4*)(A + (size_t)(m0 + row) * lda + k0 + kq);
        float4 bv = *(const float4*)(B + (size_t)(k0 + kk) * ldb + n0 + nq);
        As[kq + 0][row] = av.x; As[kq + 1][row] = av.y;
        As[kq + 2][row] = av.z; As[kq + 3][row] = av.w;
        *(float4*)&Bs[kk][nq] = bv;
        __syncthreads();
#pragma unroll
        for (int k = 0; k < 16; ++k) {
            float4 a = *(const float4*)&As[k][tm * 4];
            float4 b = *(const float4*)&Bs[k][tn * 4];
            acc[0][0] += a.x * b.x; acc[0][1] += a.x * b.y; acc[0][2] += a.x * b.z; acc[0][3] += a.x * b.w;
            acc[1][0] += a.y * b.x; acc[1][1] += a.y * b.y; acc[1][2] += a.y * b.z; acc[1][3] += a.y * b.w;
            acc[2][0] += a.z * b.x; acc[2][1] += a.z * b.y; acc[2][2] += a.z * b.z; acc[2][3] += a.z * b.w;
            acc[3][0] += a.w * b.x; acc[3][1] += a.w * b.y; acc[3][2] += a.w * b.z; acc[3][3] += a.w * b.w;
        }
        __syncthreads();
    }

#pragma unroll
    for (int i = 0; i < 4; ++i) {
        float4 r;
        r.x = acc[i][0]; r.y = acc[i][1]; r.z = acc[i][2]; r.w = acc[i][3];
        *(float4*)(C + (size_t)(m0 + tm * 4 + i) * ldc + n0 + tn * 4) = r;
    }
}

// ---------------------------------------------------------------------------
// Fused attention step (incl. dec-projection): per block b:
//   dec[a]  = sum_k h[b,k] W_dec[k,a] + b_att[a]
//   scores -> softmax -> ctx
//   x_cat[b] = [ emb[tok_t[b]] (512) | ctx (512) ]
// 512 threads (8 waves).
// ---------------------------------------------------------------------------
__global__ __launch_bounds__(512) void attn_step(
    const float* __restrict__ encf,   // [64,128,512]
    const float* __restrict__ encp,   // [64,128,256]
    const float* __restrict__ W_dec,  // [512,256]
    const float* __restrict__ b_att,  // [256]
    const float* __restrict__ v_att,  // [256]
    const float* __restrict__ emb,    // [8192,512]
    const int*   __restrict__ tgt,    // [64,32]
    const float* __restrict__ h,      // [64,512]
    float* __restrict__ x_cat,        // [64,1024]
    int t)
{
    const int b = blockIdx.x;
    const int tid = threadIdx.x;
    __shared__ float sh[512];
    __shared__ float sdec[256];
    __shared__ float sv[256];
    __shared__ float sw[128];
    __shared__ float st[128];

    sh[tid] = h[(size_t)b * 512 + tid];
    if (tid < 256) sv[tid] = v_att[tid];
    __syncthreads();

    // dec projection: threads 0..255, coalesced W_dec row reads
    if (tid < 256) {
        float s = b_att[tid];
#pragma unroll 4
        for (int k = 0; k < 512; ++k) s += sh[k] * W_dec[(size_t)k * 256 + tid];
        sdec[tid] = s;
    }
    __syncthreads();

    const int wave = tid >> 6, lane = tid & 63;
    for (int s = wave; s < 128; s += 8) {
        const float* ep = encp + ((size_t)b * 128 + s) * 256;
        float sum = 0.f;
#pragma unroll
        for (int i = 0; i < 4; ++i) {
            int a = lane + 64 * i;
            sum += tanhf(ep[a] + sdec[a]) * sv[a];
        }
#pragma unroll
        for (int off = 32; off > 0; off >>= 1) sum += __shfl_down(sum, off);
        if (lane == 0) sw[s] = sum;
    }
    __syncthreads();

    // softmax over sw[0..127]
    if (tid < 128) st[tid] = sw[tid];
    __syncthreads();
    for (int off = 64; off > 0; off >>= 1) {
        if (tid < off) st[tid] = fmaxf(st[tid], st[tid + off]);
        __syncthreads();
    }
    const float mx = st[0];
    __syncthreads();
    if (tid < 128) { float e = expf(sw[tid] - mx); sw[tid] = e; st[tid] = e; }
    __syncthreads();
    for (int off = 64; off > 0; off >>= 1) {
        if (tid < off) st[tid] += st[tid + off];
        __syncthreads();
    }
    const float inv = 1.f / st[0];

    // ctx[e] = sum_s w[s] * encf[b,s,e]
    float cv = 0.f;
    const float* ef = encf + (size_t)b * 128 * 512 + tid;
#pragma unroll 4
    for (int s = 0; s < 128; ++s) cv += sw[s] * ef[(size_t)s * 512];

    const int tok = (t == 0) ? 0 : tgt[b * TT + (t - 1)];
    float* xr = x_cat + (size_t)b * 1024;
    xr[tid]       = emb[(size_t)tok * 512 + tid];  // x_emb
    xr[512 + tid] = cv * inv;                      // ctx
}

// ---------------------------------------------------------------------------
// LSTM pointwise + out_x assembly ([h_new | ctx])
// ---------------------------------------------------------------------------
__global__ __launch_bounds__(256) void lstm_point(
    const float* __restrict__ gates,  // [64,2048] : i|f|g|o
    float* __restrict__ h, float* __restrict__ c,
    const float* __restrict__ x_cat,  // [64,1024] (ctx at +512)
    float* __restrict__ out_x)        // [64,1024]
{
    const int idx = blockIdx.x * 256 + threadIdx.x;  // 0..32767
    const int b = idx >> 9, u = idx & 511;
    const float* g = gates + (size_t)b * 2048;
    const float gi = g[u], gf = g[512 + u], gg = g[1024 + u], go = g[1536 + u];
    const float si = 1.f / (1.f + expf(-gi));
    const float sf = 1.f / (1.f + expf(-gf));
    const float so = 1.f / (1.f + expf(-go));
    const float cn = sf * c[idx] + si * tanhf(gg);
    const float hn = so * tanhf(cn);
    c[idx] = cn;
    h[idx] = hn;
    out_x[(size_t)b * 1024 + u]       = hn;
    out_x[(size_t)b * 1024 + 512 + u] = x_cat[(size_t)b * 1024 + 512 + u];
}

// ---------------------------------------------------------------------------
__global__ void k_zero(float* p, int n) {
    int i = blockIdx.x * 256 + threadIdx.x;
    if (i < n) p[i] = 0.f;
}

__global__ void k_biascomb(const float* a, const float* b, float* o) {
    int i = blockIdx.x * 256 + threadIdx.x;
    if (i < 2048) o[i] = a[i] + b[i];
}

// ---------------------------------------------------------------------------
extern "C" void kernel_launch(void* const* d_in, const int* in_sizes, int n_in,
                              void* d_out, int out_size, void* d_ws, size_t ws_size,
                              hipStream_t stream)
{
    (void)in_sizes; (void)n_in; (void)out_size; (void)ws_size;
    const float* encf  = (const float*)d_in[0];   // [64,128,512]
    const int*   tgt   = (const int*)  d_in[1];   // [64,32]
    const float* emb   = (const float*)d_in[2];   // [8192,512]
    const float* W_enc = (const float*)d_in[3];   // [512,256]
    const float* W_dec = (const float*)d_in[4];   // [512,256]
    const float* b_att = (const float*)d_in[5];   // [256]
    const float* v_att = (const float*)d_in[6];   // [256]
    const float* W_ih  = (const float*)d_in[7];   // [2048,1024]
    const float* W_hh  = (const float*)d_in[8];   // [2048,512]
    const float* b_ih  = (const float*)d_in[9];   // [2048]
    const float* b_hh  = (const float*)d_in[10];  // [2048]
    const float* W_out = (const float*)d_in[11];  // [8192,1024]
    const float* b_out = (const float*)d_in[12];  // [8192]
    float* out = (float*)d_out;                   // [64,32,8192]

    // Workspace budget kept small (~9.7 MB) — Round-0 failure was most likely
    // d_ws overflow (23.5 MB) corrupting the harness's pristine input copies.
    float* ws = (float*)d_ws;
    size_t off = 0;
    auto alloc = [&](size_t n) { float* p = ws + off; off += (n + 255) & ~(size_t)255; return p; };
    float* encp  = alloc((size_t)BB * SS * AA);   // 2,097,152
    float* biasc = alloc(2048);
    float* hbuf  = alloc((size_t)BB * HH);        // 32768
    float* cbuf  = alloc((size_t)BB * HH);        // 32768
    float* xcat  = alloc((size_t)BB * 1024);      // 65536
    float* gates = alloc((size_t)BB * 2048);      // 131072
    float* outx  = alloc((size_t)BB * 1024);      // 65536
    // total ~2.43M floats ~9.7 MB

    // ---- setup ----
    k_zero<<<(2 * BB * HH + 255) / 256, 256, 0, stream>>>(hbuf, 2 * BB * HH);  // h,c (contiguous)
    k_biascomb<<<8, 256, 0, stream>>>(b_ih, b_hh, biasc);

    // enc_proj: [8192,256] = encf[8192,512] @ W_enc[512,256]
    gemm_nn<<<dim3(BB * SS / 64, AA / 64), 256, 0, stream>>>(
        encf, EE, W_enc, AA, encp, AA, EE);

    // ---- 32 sequential decode steps ----
    for (int t = 0; t < TT; ++t) {
        // attention (incl. dec projection) + x_cat = [emb|ctx]
        attn_step<<<BB, 512, 0, stream>>>(encf, encp, W_dec, b_att, v_att,
                                          emb, tgt, hbuf, xcat, t);
        // gates = x_cat @ W_ih^T + (b_ih+b_hh)
        gemm_nt<<<dim3(1, 2048 / 64), 256, 0, stream>>>(
            xcat, 1024, W_ih, 1024, gates, 2048, 0, biasc, 1024, 0);
        // gates += h @ W_hh^T
        gemm_nt<<<dim3(1, 2048 / 64), 256, 0, stream>>>(
            hbuf, HH, W_hh, HH, gates, 2048, 0, nullptr, HH, 1);
        // LSTM pointwise, h/c update, out_x = [h_new | ctx]
        lstm_point<<<BB * HH / 256, 256, 0, stream>>>(gates, hbuf, cbuf, xcat, outx);
        // logits: out[:, t, :] = out_x @ W_out^T + b_out
        gemm_nt<<<dim3(1, VV / 64), 256, 0, stream>>>(
            outx, 1024, W_out, 1024, out, TT * VV, t * VV, b_out, 1024, 0);
    }
}

// Round 3
// 3002.349 us; speedup vs baseline: 2.5306x; 2.5306x over previous
//
#include <hip/hip_runtime.h>
#include <math.h>

// B=64, S=128, E=512, H=512, A=256, V=8192, T=32
#define BB 64
#define SS 128
#define EE 512
#define HH 512
#define AA 256
#define VV 8192
#define TT 32

typedef __bf16 bf16x8 __attribute__((ext_vector_type(8)));
typedef float  f32x4  __attribute__((ext_vector_type(4)));

__device__ __forceinline__ bf16x8 cvt_f8(const float* __restrict__ p) {
    float4 u = *(const float4*)p;
    float4 v = *(const float4*)(p + 4);
    bf16x8 r;
    r[0] = (__bf16)u.x; r[1] = (__bf16)u.y; r[2] = (__bf16)u.z; r[3] = (__bf16)u.w;
    r[4] = (__bf16)v.x; r[5] = (__bf16)v.y; r[6] = (__bf16)v.z; r[7] = (__bf16)v.w;
    return r;
}

// ---------------------------------------------------------------------------
// fp32 GEMM (NN): C[M,N] = A[M,K] * B[K,N]. One-time enc_proj only.
// ---------------------------------------------------------------------------
__global__ __launch_bounds__(256) void gemm_nn(
    const float* __restrict__ A, int lda,
    const float* __restrict__ B, int ldb,
    float* __restrict__ C, int ldc, int K)
{
    __shared__ float As[16][68];
    __shared__ float Bs[16][68];
    const int tid = threadIdx.x;
    const int m0 = blockIdx.x * 64, n0 = blockIdx.y * 64;
    const int row = tid >> 2, kq = (tid & 3) * 4;
    const int kk = tid >> 4, nq = (tid & 15) * 4;
    const int tm = tid >> 4, tn = tid & 15;
    float acc[4][4] = {};
    for (int k0 = 0; k0 < K; k0 += 16) {
        float4 av = *(const float4*)(A + (size_t)(m0 + row) * lda + k0 + kq);
        float4 bv = *(const float4*)(B + (size_t)(k0 + kk) * ldb + n0 + nq);
        As[kq + 0][row] = av.x; As[kq + 1][row] = av.y;
        As[kq + 2][row] = av.z; As[kq + 3][row] = av.w;
        *(float4*)&Bs[kk][nq] = bv;
        __syncthreads();
#pragma unroll
        for (int k = 0; k < 16; ++k) {
            float4 a = *(const float4*)&As[k][tm * 4];
            float4 b = *(const float4*)&Bs[k][tn * 4];
            acc[0][0] += a.x * b.x; acc[0][1] += a.x * b.y; acc[0][2] += a.x * b.z; acc[0][3] += a.x * b.w;
            acc[1][0] += a.y * b.x; acc[1][1] += a.y * b.y; acc[1][2] += a.y * b.z; acc[1][3] += a.y * b.w;
            acc[2][0] += a.z * b.x; acc[2][1] += a.z * b.y; acc[2][2] += a.z * b.z; acc[2][3] += a.z * b.w;
            acc[3][0] += a.w * b.x; acc[3][1] += a.w * b.y; acc[3][2] += a.w * b.z; acc[3][3] += a.w * b.w;
        }
        __syncthreads();
    }
#pragma unroll
    for (int i = 0; i < 4; ++i) {
        float4 r = make_float4(acc[i][0], acc[i][1], acc[i][2], acc[i][3]);
        *(float4*)(C + (size_t)(m0 + tm * 4 + i) * ldc + n0 + tn * 4) = r;
    }
}

// ---------------------------------------------------------------------------
// dec = h @ W_dec + b_att  : [64,256], K=512.  grid 64 x 512thr, split-K 2.
// ---------------------------------------------------------------------------
__global__ __launch_bounds__(512) void dec_proj(
    const float* __restrict__ h, const float* __restrict__ W_dec,
    const float* __restrict__ b_att, float* __restrict__ dec)
{
    const int b = blockIdx.x;
    const int tid = threadIdx.x;
    const int a = tid & 255, kh = tid >> 8;
    __shared__ float sh[512];
    __shared__ float part[2][256];
    sh[tid] = h[(size_t)b * 512 + tid];
    __syncthreads();
    float s = 0.f;
    const float* w = W_dec + (size_t)(kh * 256) * 256 + a;
    const float* hh = sh + kh * 256;
#pragma unroll 8
    for (int k = 0; k < 256; ++k) s += hh[k] * w[(size_t)k * 256];
    part[kh][a] = s;
    __syncthreads();
    if (tid < 256) dec[b * 256 + a] = part[0][a] + part[1][a] + b_att[a];
}

// ---------------------------------------------------------------------------
// scores[b,s] = sum_a tanh(encp[b,s,a] + dec[b,a]) * v[a].  grid (64,4) x 256.
// ---------------------------------------------------------------------------
__global__ __launch_bounds__(256) void attn_scores(
    const float* __restrict__ encp, const float* __restrict__ dec,
    const float* __restrict__ v_att, float* __restrict__ scores)
{
    const int b = blockIdx.x;
    const int s0 = blockIdx.y * 32;
    const int tid = threadIdx.x;
    __shared__ float sdec[256], sv[256];
    sdec[tid] = dec[b * 256 + tid];
    sv[tid] = v_att[tid];
    __syncthreads();
    const int w = tid >> 6, lane = tid & 63;
#pragma unroll
    for (int i = 0; i < 8; ++i) {
        const int s = s0 + i * 4 + w;
        const float* ep = encp + ((size_t)b * 128 + s) * 256;
        float sum = 0.f;
#pragma unroll
        for (int c = 0; c < 4; ++c) {
            int a = lane + 64 * c;
            sum += tanhf(ep[a] + sdec[a]) * sv[a];
        }
#pragma unroll
        for (int off = 32; off > 0; off >>= 1) sum += __shfl_down(sum, off);
        if (lane == 0) scores[b * 128 + s] = sum;
    }
}

// ---------------------------------------------------------------------------
// softmax + ctx + emb gather -> xh_ce[b] = [ctx(512) | emb(512)] bf16.
// grid (64,2) x 256 : block handles 256 of the 512 e-dims.
// ---------------------------------------------------------------------------
__global__ __launch_bounds__(256) void attn_ctx(
    const float* __restrict__ encf, const float* __restrict__ scores,
    const float* __restrict__ emb, const int* __restrict__ tgt,
    __bf16* __restrict__ xh_ce, int t)
{
    const int b = blockIdx.x;
    const int e = blockIdx.y * 256 + threadIdx.x;
    const int tid = threadIdx.x;
    __shared__ float sw[128], st[128];
    if (tid < 128) { float v = scores[b * 128 + tid]; sw[tid] = v; st[tid] = v; }
    __syncthreads();
    for (int off = 64; off > 0; off >>= 1) {
        if (tid < off) st[tid] = fmaxf(st[tid], st[tid + off]);
        __syncthreads();
    }
    const float mx = st[0];
    __syncthreads();
    if (tid < 128) { float ex = expf(sw[tid] - mx); sw[tid] = ex; st[tid] = ex; }
    __syncthreads();
    for (int off = 64; off > 0; off >>= 1) {
        if (tid < off) st[tid] += st[tid + off];
        __syncthreads();
    }
    const float inv = 1.f / st[0];

    float cv = 0.f;
    const float* ef = encf + (size_t)b * (SS * EE) + e;
#pragma unroll 8
    for (int s = 0; s < 128; ++s) cv += sw[s] * ef[(size_t)s * 512];

    __bf16* xr = xh_ce + (size_t)b * 1024;
    xr[e] = (__bf16)(cv * inv);                       // ctx
    const int tok = (t == 0) ? 0 : tgt[b * TT + t - 1];
    xr[512 + e] = (__bf16)emb[(size_t)tok * 512 + e]; // emb
}

// ---------------------------------------------------------------------------
// Gates GEMM (bf16 MFMA) + fused LSTM pointwise.
// C[64,2048] over K=1536 = [h(512)|ctx(512)|emb(512)], weight rows permuted
// on the fly: col n <-> orig gate-row (n&3)*512 + (n>>2) so each 64-col block
// holds 16 complete (i,f,g,o) quads.  grid 32 x 256thr.
// ---------------------------------------------------------------------------
__global__ __launch_bounds__(256) void gemm_gates_lstm(
    const __bf16* __restrict__ h_old,   // [64][512] bf16
    const __bf16* __restrict__ xh_ce,   // [64][1024] = [ctx|emb]
    const float* __restrict__ W_ih,     // [2048][1024]
    const float* __restrict__ W_hh,     // [2048][512]
    const float* __restrict__ b_ih, const float* __restrict__ b_hh,
    float* __restrict__ hbuf, float* __restrict__ cbuf,
    __bf16* __restrict__ h_new)         // [64][512] bf16 (other buffer)
{
    __shared__ __bf16 Bs[64][40];
    __shared__ float  Cf[64][68];
    const int tid = threadIdx.x;
    const int n0 = blockIdx.x * 64;
    const int wv = tid >> 6, lane = tid & 63;
    const int quad = lane >> 4, l16 = lane & 15;
    const int row = tid >> 2, seg = tid & 3;
    const int nglob = n0 + row;
    const int j = ((nglob & 3) << 9) + (nglob >> 2);   // orig weight row

    f32x4 acc0 = {0.f,0.f,0.f,0.f}, acc1 = acc0, acc2 = acc0, acc3 = acc0;

    const __bf16* aH = h_old + (size_t)(wv * 16 + l16) * 512 + quad * 8;
    const __bf16* aX = xh_ce + (size_t)(wv * 16 + l16) * 1024 + quad * 8;

    for (int k0 = 0; k0 < 1536; k0 += 32) {
        const int k = k0 + seg * 8;
        const float* src = (k < 512)  ? (W_hh + (size_t)j * 512 + k)
                         : (k < 1024) ? (W_ih + (size_t)j * 1024 + k)
                                      : (W_ih + (size_t)j * 1024 + (k - 1024));
        bf16x8 pk = cvt_f8(src);
        __syncthreads();
        *(bf16x8*)&Bs[row][seg * 8] = pk;
        __syncthreads();
        bf16x8 af = (k0 < 512) ? *(const bf16x8*)(aH + k0)
                               : *(const bf16x8*)(aX + (k0 - 512));
        bf16x8 b0 = *(const bf16x8*)&Bs[ 0 + l16][quad * 8];
        bf16x8 b1 = *(const bf16x8*)&Bs[16 + l16][quad * 8];
        bf16x8 b2 = *(const bf16x8*)&Bs[32 + l16][quad * 8];
        bf16x8 b3 = *(const bf16x8*)&Bs[48 + l16][quad * 8];
        acc0 = __builtin_amdgcn_mfma_f32_16x16x32_bf16(af, b0, acc0, 0, 0, 0);
        acc1 = __builtin_amdgcn_mfma_f32_16x16x32_bf16(af, b1, acc1, 0, 0, 0);
        acc2 = __builtin_amdgcn_mfma_f32_16x16x32_bf16(af, b2, acc2, 0, 0, 0);
        acc3 = __builtin_amdgcn_mfma_f32_16x16x32_bf16(af, b3, acc3, 0, 0, 0);
    }
    __syncthreads();
#pragma unroll
    for (int r = 0; r < 4; ++r) {
        Cf[wv * 16 + quad * 4 + r][ 0 + l16] = acc0[r];
        Cf[wv * 16 + quad * 4 + r][16 + l16] = acc1[r];
        Cf[wv * 16 + quad * 4 + r][32 + l16] = acc2[r];
        Cf[wv * 16 + quad * 4 + r][48 + l16] = acc3[r];
    }
    __syncthreads();
    const int U0 = n0 >> 2;
    for (int it = tid; it < 1024; it += 256) {
        const int b = it >> 4, ul = it & 15;
        const int ug = U0 + ul;
        const float gi = Cf[b][4 * ul + 0] + b_ih[ug]        + b_hh[ug];
        const float gf = Cf[b][4 * ul + 1] + b_ih[512 + ug]  + b_hh[512 + ug];
        const float gg = Cf[b][4 * ul + 2] + b_ih[1024 + ug] + b_hh[1024 + ug];
        const float go = Cf[b][4 * ul + 3] + b_ih[1536 + ug] + b_hh[1536 + ug];
        const float si = 1.f / (1.f + expf(-gi));
        const float sf = 1.f / (1.f + expf(-gf));
        const float so = 1.f / (1.f + expf(-go));
        const float cn = sf * cbuf[b * 512 + ug] + si * tanhf(gg);
        const float hn = so * tanhf(cn);
        cbuf[b * 512 + ug] = cn;
        hbuf[b * 512 + ug] = hn;
        h_new[(size_t)b * 512 + ug] = (__bf16)hn;
    }
}

// ---------------------------------------------------------------------------
// Logits GEMM (bf16 MFMA): out[:,t,:] = [h_new|ctx] @ W_out^T + b_out.
// grid 128 x 256thr, K=1024.
// ---------------------------------------------------------------------------
__global__ __launch_bounds__(256) void gemm_out(
    const __bf16* __restrict__ h_new,   // [64][512]
    const __bf16* __restrict__ xh_ce,   // [64][1024], ctx = first 512
    const float* __restrict__ W_out,    // [8192][1024]
    const float* __restrict__ b_out,
    float* __restrict__ out, int t)
{
    __shared__ __bf16 Bs[64][40];
    const int tid = threadIdx.x;
    const int n0 = blockIdx.x * 64;
    const int wv = tid >> 6, lane = tid & 63;
    const int quad = lane >> 4, l16 = lane & 15;
    const int row = tid >> 2, seg = tid & 3;

    f32x4 acc0 = {0.f,0.f,0.f,0.f}, acc1 = acc0, acc2 = acc0, acc3 = acc0;

    const __bf16* aH = h_new + (size_t)(wv * 16 + l16) * 512 + quad * 8;
    const __bf16* aX = xh_ce + (size_t)(wv * 16 + l16) * 1024 + quad * 8;
    const float*  bsrc = W_out + (size_t)(n0 + row) * 1024 + seg * 8;

    for (int k0 = 0; k0 < 1024; k0 += 32) {
        bf16x8 pk = cvt_f8(bsrc + k0);
        __syncthreads();
        *(bf16x8*)&Bs[row][seg * 8] = pk;
        __syncthreads();
        bf16x8 af = (k0 < 512) ? *(const bf16x8*)(aH + k0)
                               : *(const bf16x8*)(aX + (k0 - 512));
        bf16x8 b0 = *(const bf16x8*)&Bs[ 0 + l16][quad * 8];
        bf16x8 b1 = *(const bf16x8*)&Bs[16 + l16][quad * 8];
        bf16x8 b2 = *(const bf16x8*)&Bs[32 + l16][quad * 8];
        bf16x8 b3 = *(const bf16x8*)&Bs[48 + l16][quad * 8];
        acc0 = __builtin_amdgcn_mfma_f32_16x16x32_bf16(af, b0, acc0, 0, 0, 0);
        acc1 = __builtin_amdgcn_mfma_f32_16x16x32_bf16(af, b1, acc1, 0, 0, 0);
        acc2 = __builtin_amdgcn_mfma_f32_16x16x32_bf16(af, b2, acc2, 0, 0, 0);
        acc3 = __builtin_amdgcn_mfma_f32_16x16x32_bf16(af, b3, acc3, 0, 0, 0);
    }
    const int m = wv * 16 + quad * 4;
    const int nb = n0 + l16;
    float* op = out + (size_t)t * VV + nb;
#pragma unroll
    for (int r = 0; r < 4; ++r) {
        float* orow = op + (size_t)(m + r) * (TT * VV);
        orow[ 0] = acc0[r] + b_out[nb +  0];
        orow[16] = acc1[r] + b_out[nb + 16];
        orow[32] = acc2[r] + b_out[nb + 32];
        orow[48] = acc3[r] + b_out[nb + 48];
    }
}

// ---------------------------------------------------------------------------
__global__ void k_zero_f(float* p, int n) {
    int i = blockIdx.x * 256 + threadIdx.x;
    if (i < n) p[i] = 0.f;
}
__global__ void k_zero_bf(__bf16* p, int n) {
    int i = blockIdx.x * 256 + threadIdx.x;
    if (i < n) p[i] = (__bf16)0.f;
}

// ---------------------------------------------------------------------------
extern "C" void kernel_launch(void* const* d_in, const int* in_sizes, int n_in,
                              void* d_out, int out_size, void* d_ws, size_t ws_size,
                              hipStream_t stream)
{
    (void)in_sizes; (void)n_in; (void)out_size; (void)ws_size;
    const float* encf  = (const float*)d_in[0];
    const int*   tgt   = (const int*)  d_in[1];
    const float* emb   = (const float*)d_in[2];
    const float* W_enc = (const float*)d_in[3];
    const float* W_dec = (const float*)d_in[4];
    const float* b_att = (const float*)d_in[5];
    const float* v_att = (const float*)d_in[6];
    const float* W_ih  = (const float*)d_in[7];
    const float* W_hh  = (const float*)d_in[8];
    const float* b_ih  = (const float*)d_in[9];
    const float* b_hh  = (const float*)d_in[10];
    const float* W_out = (const float*)d_in[11];
    const float* b_out = (const float*)d_in[12];
    float* out = (float*)d_out;

    // workspace (~8.9 MB, well under the ~10 MB proven-safe budget)
    float* ws = (float*)d_ws;
    size_t off = 0;
    auto alloc = [&](size_t n) { float* p = ws + off; off += (n + 255) & ~(size_t)255; return p; };
    float*  encp   = alloc((size_t)BB * SS * AA);   // 2.10M fl
    float*  hbuf   = alloc((size_t)BB * HH);
    float*  cbuf   = alloc((size_t)BB * HH);
    float*  dec    = alloc((size_t)BB * AA);
    float*  scores = alloc((size_t)BB * SS);
    __bf16* xh_ce  = (__bf16*)alloc((size_t)BB * 1024 / 2);   // 64x1024 bf16
    __bf16* hb0    = (__bf16*)alloc((size_t)BB * HH / 2);     // h ping
    __bf16* hb1    = (__bf16*)alloc((size_t)BB * HH / 2);     // h pong

    // setup: zero h, c, h-bf16 ping buffer
    k_zero_f<<<(2 * BB * HH + 255) / 256, 256, 0, stream>>>(hbuf, 2 * BB * HH);
    k_zero_bf<<<(BB * HH + 255) / 256, 256, 0, stream>>>(hb0, BB * HH);
    // enc_proj (one-time, fp32)
    gemm_nn<<<dim3(BB * SS / 64, AA / 64), 256, 0, stream>>>(encf, EE, W_enc, AA, encp, AA, EE);

    for (int t = 0; t < TT; ++t) {
        __bf16* hold = (t & 1) ? hb1 : hb0;
        __bf16* hnew = (t & 1) ? hb0 : hb1;
        dec_proj<<<BB, 512, 0, stream>>>(hbuf, W_dec, b_att, dec);
        attn_scores<<<dim3(BB, 4), 256, 0, stream>>>(encp, dec, v_att, scores);
        attn_ctx<<<dim3(BB, 2), 256, 0, stream>>>(encf, scores, emb, tgt, xh_ce, t);
        gemm_gates_lstm<<<2048 / 64, 256, 0, stream>>>(hold, xh_ce, W_ih, W_hh,
                                                       b_ih, b_hh, hbuf, cbuf, hnew);
        gemm_out<<<VV / 64, 256, 0, stream>>>(hnew, xh_ce, W_out, b_out, out, t);
    }
}

// Round 4
// 2123.888 us; speedup vs baseline: 3.5773x; 1.4136x over previous
//
#include <hip/hip_runtime.h>
#include <math.h>

// B=64, S=128, E=512, H=512, A=256, V=8192, T=32
#define BB 64
#define SS 128
#define EE 512
#define HH 512
#define AA 256
#define VV 8192
#define TT 32

typedef __bf16 bf16x8 __attribute__((ext_vector_type(8)));
typedef float  f32x4  __attribute__((ext_vector_type(4)));

__device__ __forceinline__ bf16x8 cvt_v(float4 u, float4 v) {
    bf16x8 r;
    r[0] = (__bf16)u.x; r[1] = (__bf16)u.y; r[2] = (__bf16)u.z; r[3] = (__bf16)u.w;
    r[4] = (__bf16)v.x; r[5] = (__bf16)v.y; r[6] = (__bf16)v.z; r[7] = (__bf16)v.w;
    return r;
}

// ---------------------------------------------------------------------------
// fp32 GEMM (NN): C[M,N] = A[M,K] * B[K,N]. One-time enc_proj only.
// ---------------------------------------------------------------------------
__global__ __launch_bounds__(256) void gemm_nn(
    const float* __restrict__ A, int lda,
    const float* __restrict__ B, int ldb,
    float* __restrict__ C, int ldc, int K)
{
    __shared__ float As[16][68];
    __shared__ float Bs[16][68];
    const int tid = threadIdx.x;
    const int m0 = blockIdx.x * 64, n0 = blockIdx.y * 64;
    const int row = tid >> 2, kq = (tid & 3) * 4;
    const int kk = tid >> 4, nq = (tid & 15) * 4;
    const int tm = tid >> 4, tn = tid & 15;
    float acc[4][4] = {};
    for (int k0 = 0; k0 < K; k0 += 16) {
        float4 av = *(const float4*)(A + (size_t)(m0 + row) * lda + k0 + kq);
        float4 bv = *(const float4*)(B + (size_t)(k0 + kk) * ldb + n0 + nq);
        As[kq + 0][row] = av.x; As[kq + 1][row] = av.y;
        As[kq + 2][row] = av.z; As[kq + 3][row] = av.w;
        *(float4*)&Bs[kk][nq] = bv;
        __syncthreads();
#pragma unroll
        for (int k = 0; k < 16; ++k) {
            float4 a = *(const float4*)&As[k][tm * 4];
            float4 b = *(const float4*)&Bs[k][tn * 4];
            acc[0][0] += a.x * b.x; acc[0][1] += a.x * b.y; acc[0][2] += a.x * b.z; acc[0][3] += a.x * b.w;
            acc[1][0] += a.y * b.x; acc[1][1] += a.y * b.y; acc[1][2] += a.y * b.z; acc[1][3] += a.y * b.w;
            acc[2][0] += a.z * b.x; acc[2][1] += a.z * b.y; acc[2][2] += a.z * b.z; acc[2][3] += a.z * b.w;
            acc[3][0] += a.w * b.x; acc[3][1] += a.w * b.y; acc[3][2] += a.w * b.z; acc[3][3] += a.w * b.w;
        }
        __syncthreads();
    }
#pragma unroll
    for (int i = 0; i < 4; ++i) {
        float4 r = make_float4(acc[i][0], acc[i][1], acc[i][2], acc[i][3]);
        *(float4*)(C + (size_t)(m0 + tm * 4 + i) * ldc + n0 + tn * 4) = r;
    }
}

// ---------------------------------------------------------------------------
// Fused attention step: dec-proj + scores + softmax + ctx + emb gather.
// One block per batch b, 1024 threads (16 waves).
//   xh_ce[b] = [ctx(512) | emb(512)] bf16
// ---------------------------------------------------------------------------
__global__ __launch_bounds__(1024) void attn_fused(
    const float* __restrict__ encf,   // [64,128,512]
    const float* __restrict__ encp,   // [64,128,256]
    const float* __restrict__ W_dec,  // [512,256]
    const float* __restrict__ b_att,  // [256]
    const float* __restrict__ v_att,  // [256]
    const float* __restrict__ emb,    // [8192,512]
    const int*   __restrict__ tgt,    // [64,32]
    const float* __restrict__ h,      // [64,512] fp32
    __bf16* __restrict__ xh_ce,       // [64,1024]
    int t)
{
    const int b = blockIdx.x;
    const int tid = threadIdx.x;
    __shared__ float sh[512];
    __shared__ float sdec[256];
    __shared__ float sv[256];
    __shared__ float sw[128], st[128];
    __shared__ float part[4][256];
    __shared__ float cpart[2][512];

    if (tid < 512) sh[tid] = h[(size_t)b * 512 + tid];
    else if (tid < 768) sv[tid - 512] = v_att[tid - 512];
    __syncthreads();

    // Phase 1: dec[a] = sum_k h[k] W_dec[k,a]  (split-K 4)
    {
        const int a = tid & 255, kq = tid >> 8;
        const float* w = W_dec + (size_t)kq * 128 * 256 + a;
        const float* hp = sh + kq * 128;
        float s = 0.f;
#pragma unroll 8
        for (int k = 0; k < 128; ++k) s += hp[k] * w[(size_t)k * 256];
        part[kq][a] = s;
    }
    __syncthreads();
    if (tid < 256)
        sdec[tid] = part[0][tid] + part[1][tid] + part[2][tid] + part[3][tid] + b_att[tid];
    __syncthreads();

    // Phase 2: scores (16 waves x 8 s)
    {
        const int wv = tid >> 6, lane = tid & 63;
#pragma unroll
        for (int i = 0; i < 8; ++i) {
            const int s = wv * 8 + i;
            const float* ep = encp + ((size_t)b * 128 + s) * 256;
            float sum = 0.f;
#pragma unroll
            for (int c = 0; c < 4; ++c) {
                int a = lane + 64 * c;
                sum += tanhf(ep[a] + sdec[a]) * sv[a];
            }
#pragma unroll
            for (int off = 32; off > 0; off >>= 1) sum += __shfl_down(sum, off);
            if (lane == 0) sw[s] = sum;
        }
    }
    __syncthreads();

    // Phase 3: softmax (unnormalized exp in sw, sum in st[0])
    if (tid < 128) st[tid] = sw[tid];
    __syncthreads();
    for (int off = 64; off > 0; off >>= 1) {
        if (tid < off) st[tid] = fmaxf(st[tid], st[tid + off]);
        __syncthreads();
    }
    const float mx = st[0];
    __syncthreads();
    if (tid < 128) { float ex = expf(sw[tid] - mx); sw[tid] = ex; st[tid] = ex; }
    __syncthreads();
    for (int off = 64; off > 0; off >>= 1) {
        if (tid < off) st[tid] += st[tid + off];
        __syncthreads();
    }

    // Phase 4: ctx (split-S 2)
    {
        const int e = tid & 511, half = tid >> 9;
        const float* ef = encf + (size_t)b * (SS * EE) + (size_t)half * 64 * 512 + e;
        const float* wp = sw + half * 64;
        float cv = 0.f;
#pragma unroll 8
        for (int s = 0; s < 64; ++s) cv += wp[s] * ef[(size_t)s * 512];
        cpart[half][e] = cv;
    }
    __syncthreads();
    const float inv = 1.f / st[0];
    if (tid < 512) {
        xh_ce[(size_t)b * 1024 + tid] = (__bf16)((cpart[0][tid] + cpart[1][tid]) * inv);
    } else {
        const int e = tid - 512;
        const int tok = (t == 0) ? 0 : tgt[b * TT + t - 1];
        xh_ce[(size_t)b * 1024 + 512 + e] = (__bf16)emb[(size_t)tok * 512 + e];
    }
}

// ---------------------------------------------------------------------------
// Gates GEMM (bf16 MFMA, pipelined BK=64) + fused LSTM pointwise.
// C[64,2048] over K=1536 = [h|ctx|emb]; weight rows permuted:
// col n <-> orig gate row (n&3)*512 + (n>>2).  grid 32 x 256thr.
// ---------------------------------------------------------------------------
__global__ __launch_bounds__(256) void gemm_gates_lstm(
    const __bf16* __restrict__ h_old,   // [64][512]
    const __bf16* __restrict__ xh_ce,   // [64][1024] = [ctx|emb]
    const float* __restrict__ W_ih,     // [2048][1024]
    const float* __restrict__ W_hh,     // [2048][512]
    const float* __restrict__ b_ih, const float* __restrict__ b_hh,
    float* __restrict__ hbuf, float* __restrict__ cbuf,
    __bf16* __restrict__ h_new)
{
    __shared__ __bf16 Bs[2][64][72];
    __shared__ float  Cf[64][68];
    const int tid = threadIdx.x;
    const int n0 = blockIdx.x * 64;
    const int wv = tid >> 6, lane = tid & 63;
    const int quad = lane >> 4, l16 = lane & 15;
    const int row = tid >> 2, cq = tid & 3;
    const int nglob = n0 + row;
    const int j = ((nglob & 3) << 9) + (nglob >> 2);
    const float* rH = W_hh + (size_t)j * 512;
    const float* rI = W_ih + (size_t)j * 1024;

    const __bf16* aHp = h_old + (size_t)(wv * 16 + l16) * 512 + quad * 8;
    const __bf16* aXp = xh_ce + (size_t)(wv * 16 + l16) * 1024 + quad * 8;

    f32x4 acc[4] = {{0,0,0,0},{0,0,0,0},{0,0,0,0},{0,0,0,0}};

    auto wsrc = [&](int it) -> const float* {
        const int k = it * 64 + cq * 16;
        if (k < 512)  return rH + k;
        if (k < 1024) return rI + k;
        return rI + (k - 1024);
    };
#define LDW(d, p) { const float4* q = (const float4*)(p); d##0 = q[0]; d##1 = q[1]; d##2 = q[2]; d##3 = q[3]; }
    float4 wA0, wA1, wA2, wA3, wB0, wB1, wB2, wB3;
    LDW(wA, wsrc(0)); LDW(wB, wsrc(1));
    bf16x8 aC0 = *(const bf16x8*)aHp, aC1 = *(const bf16x8*)(aHp + 32);
    bf16x8 aN0, aN1;

    for (int it = 0; it < 24; ++it) {
        __bf16* dst = &Bs[it & 1][row][cq * 16];
        *(bf16x8*)dst       = cvt_v(wA0, wA1);
        *(bf16x8*)(dst + 8) = cvt_v(wA2, wA3);
        __syncthreads();
        wA0 = wB0; wA1 = wB1; wA2 = wB2; wA3 = wB3;
        if (it + 2 < 24) LDW(wB, wsrc(it + 2));
        if (it + 1 < 24) {
            const int itn = it + 1;
            const __bf16* ap = (itn < 8) ? (aHp + itn * 64) : (aXp + (itn - 8) * 64);
            aN0 = *(const bf16x8*)ap; aN1 = *(const bf16x8*)(ap + 32);
        }
#pragma unroll
        for (int c = 0; c < 4; ++c) {
            bf16x8 b0 = *(const bf16x8*)&Bs[it & 1][c * 16 + l16][quad * 8];
            bf16x8 b1 = *(const bf16x8*)&Bs[it & 1][c * 16 + l16][quad * 8 + 32];
            acc[c] = __builtin_amdgcn_mfma_f32_16x16x32_bf16(aC0, b0, acc[c], 0, 0, 0);
            acc[c] = __builtin_amdgcn_mfma_f32_16x16x32_bf16(aC1, b1, acc[c], 0, 0, 0);
        }
        aC0 = aN0; aC1 = aN1;
    }
    __syncthreads();
#pragma unroll
    for (int r = 0; r < 4; ++r) {
        Cf[wv * 16 + quad * 4 + r][ 0 + l16] = acc[0][r];
        Cf[wv * 16 + quad * 4 + r][16 + l16] = acc[1][r];
        Cf[wv * 16 + quad * 4 + r][32 + l16] = acc[2][r];
        Cf[wv * 16 + quad * 4 + r][48 + l16] = acc[3][r];
    }
    __syncthreads();
    const int U0 = n0 >> 2;
    for (int it = tid; it < 1024; it += 256) {
        const int bb = it >> 4, ul = it & 15;
        const int ug = U0 + ul;
        const float gi = Cf[bb][4 * ul + 0] + b_ih[ug]         + b_hh[ug];
        const float gf = Cf[bb][4 * ul + 1] + b_ih[512 + ug]   + b_hh[512 + ug];
        const float gg = Cf[bb][4 * ul + 2] + b_ih[1024 + ug]  + b_hh[1024 + ug];
        const float go = Cf[bb][4 * ul + 3] + b_ih[1536 + ug]  + b_hh[1536 + ug];
        const float si = 1.f / (1.f + expf(-gi));
        const float sf = 1.f / (1.f + expf(-gf));
        const float so = 1.f / (1.f + expf(-go));
        const float cn = sf * cbuf[bb * 512 + ug] + si * tanhf(gg);
        const float hn = so * tanhf(cn);
        cbuf[bb * 512 + ug] = cn;
        hbuf[bb * 512 + ug] = hn;
        h_new[(size_t)bb * 512 + ug] = (__bf16)hn;
    }
}

// ---------------------------------------------------------------------------
// Logits GEMM (bf16 MFMA, pipelined BK=64): out[:,t,:] = [h_new|ctx]@W_out^T + b_out
// grid 128 x 256thr, K=1024.
// ---------------------------------------------------------------------------
__global__ __launch_bounds__(256) void gemm_out(
    const __bf16* __restrict__ hA,      // [64][512]
    const __bf16* __restrict__ xA,      // [64][1024], ctx = first 512
    const float* __restrict__ W_out,    // [8192][1024]
    const float* __restrict__ b_out,
    float* __restrict__ out, int t)
{
    __shared__ __bf16 Bs[2][64][72];
    const int tid = threadIdx.x;
    const int n0 = blockIdx.x * 64;
    const int wv = tid >> 6, lane = tid & 63;
    const int quad = lane >> 4, l16 = lane & 15;
    const int row = tid >> 2, cq = tid & 3;
    const float* bsrc = W_out + (size_t)(n0 + row) * 1024 + cq * 16;
    const __bf16* aHp = hA + (size_t)(wv * 16 + l16) * 512 + quad * 8;
    const __bf16* aXp = xA + (size_t)(wv * 16 + l16) * 1024 + quad * 8;

    f32x4 acc[4] = {{0,0,0,0},{0,0,0,0},{0,0,0,0},{0,0,0,0}};

    float4 wA0, wA1, wA2, wA3, wB0, wB1, wB2, wB3;
    LDW(wA, bsrc); LDW(wB, bsrc + 64);
    bf16x8 aC0 = *(const bf16x8*)aHp, aC1 = *(const bf16x8*)(aHp + 32);
    bf16x8 aN0, aN1;

    for (int it = 0; it < 16; ++it) {
        __bf16* dst = &Bs[it & 1][row][cq * 16];
        *(bf16x8*)dst       = cvt_v(wA0, wA1);
        *(bf16x8*)(dst + 8) = cvt_v(wA2, wA3);
        __syncthreads();
        wA0 = wB0; wA1 = wB1; wA2 = wB2; wA3 = wB3;
        if (it + 2 < 16) LDW(wB, bsrc + (it + 2) * 64);
        if (it + 1 < 16) {
            const int itn = it + 1;
            const __bf16* ap = (itn < 8) ? (aHp + itn * 64) : (aXp + (itn - 8) * 64);
            aN0 = *(const bf16x8*)ap; aN1 = *(const bf16x8*)(ap + 32);
        }
#pragma unroll
        for (int c = 0; c < 4; ++c) {
            bf16x8 b0 = *(const bf16x8*)&Bs[it & 1][c * 16 + l16][quad * 8];
            bf16x8 b1 = *(const bf16x8*)&Bs[it & 1][c * 16 + l16][quad * 8 + 32];
            acc[c] = __builtin_amdgcn_mfma_f32_16x16x32_bf16(aC0, b0, acc[c], 0, 0, 0);
            acc[c] = __builtin_amdgcn_mfma_f32_16x16x32_bf16(aC1, b1, acc[c], 0, 0, 0);
        }
        aC0 = aN0; aC1 = aN1;
    }

    const int m = wv * 16 + quad * 4;
    const int nb = n0 + l16;
    float* op = out + (size_t)t * VV + nb;
#pragma unroll
    for (int r = 0; r < 4; ++r) {
        float* orow = op + (size_t)(m + r) * (TT * VV);
        orow[ 0] = acc[0][r] + b_out[nb +  0];
        orow[16] = acc[1][r] + b_out[nb + 16];
        orow[32] = acc[2][r] + b_out[nb + 32];
        orow[48] = acc[3][r] + b_out[nb + 48];
    }
}

// ---------------------------------------------------------------------------
__global__ void k_zero_f(float* p, int n) {
    int i = blockIdx.x * 256 + threadIdx.x;
    if (i < n) p[i] = 0.f;
}
__global__ void k_zero_bf(__bf16* p, int n) {
    int i = blockIdx.x * 256 + threadIdx.x;
    if (i < n) p[i] = (__bf16)0.f;
}

// ---------------------------------------------------------------------------
extern "C" void kernel_launch(void* const* d_in, const int* in_sizes, int n_in,
                              void* d_out, int out_size, void* d_ws, size_t ws_size,
                              hipStream_t stream)
{
    (void)in_sizes; (void)n_in; (void)out_size; (void)ws_size;
    const float* encf  = (const float*)d_in[0];
    const int*   tgt   = (const int*)  d_in[1];
    const float* emb   = (const float*)d_in[2];
    const float* W_enc = (const float*)d_in[3];
    const float* W_dec = (const float*)d_in[4];
    const float* b_att = (const float*)d_in[5];
    const float* v_att = (const float*)d_in[6];
    const float* W_ih  = (const float*)d_in[7];
    const float* W_hh  = (const float*)d_in[8];
    const float* b_ih  = (const float*)d_in[9];
    const float* b_hh  = (const float*)d_in[10];
    const float* W_out = (const float*)d_in[11];
    const float* b_out = (const float*)d_in[12];
    float* out = (float*)d_out;

    // workspace (~8.9 MB; ws proven safe at ~9.7 MB)
    float* ws = (float*)d_ws;
    size_t off = 0;
    auto alloc = [&](size_t n) { float* p = ws + off; off += (n + 255) & ~(size_t)255; return p; };
    float*  encp  = alloc((size_t)BB * SS * AA);
    float*  hbuf  = alloc((size_t)BB * HH);
    float*  cbuf  = alloc((size_t)BB * HH);
    __bf16* xh_ce = (__bf16*)alloc((size_t)BB * 1024 / 2);
    __bf16* hb0   = (__bf16*)alloc((size_t)BB * HH / 2);
    __bf16* hb1   = (__bf16*)alloc((size_t)BB * HH / 2);

    k_zero_f<<<(2 * BB * HH + 255) / 256, 256, 0, stream>>>(hbuf, 2 * BB * HH);
    k_zero_bf<<<(BB * HH + 255) / 256, 256, 0, stream>>>(hb0, BB * HH);
    gemm_nn<<<dim3(BB * SS / 64, AA / 64), 256, 0, stream>>>(encf, EE, W_enc, AA, encp, AA, EE);

    for (int t = 0; t < TT; ++t) {
        __bf16* hold = (t & 1) ? hb1 : hb0;
        __bf16* hnew = (t & 1) ? hb0 : hb1;
        attn_fused<<<BB, 1024, 0, stream>>>(encf, encp, W_dec, b_att, v_att,
                                            emb, tgt, hbuf, xh_ce, t);
        gemm_gates_lstm<<<32, 256, 0, stream>>>(hold, xh_ce, W_ih, W_hh,
                                                b_ih, b_hh, hbuf, cbuf, hnew);
        gemm_out<<<VV / 64, 256, 0, stream>>>(hnew, xh_ce, W_out, b_out, out, t);
    }
}